// Round 4
// baseline (1307.905 us; speedup 1.0000x reference)
//
#include <hip/hip_runtime.h>

#define B_ 2
#define S_ 512
#define F_ 4096
#define D_ 768
#define H_ 12

typedef __attribute__((ext_vector_type(8))) short bf16x8;
typedef __attribute__((ext_vector_type(4))) float f32x4;
typedef unsigned short u16;
typedef unsigned int u32;
typedef unsigned long long u64;

__device__ inline u16 f2bf(float f) {
  u32 u = __float_as_uint(f);
  u32 r = (u + 0x7fffu + ((u >> 16) & 1u)) >> 16;  // RNE
  return (u16)r;
}

__device__ inline void gload16(const void* g, void* l) {
  __builtin_amdgcn_global_load_lds((const __attribute__((address_space(1))) void*)g,
                                   (__attribute__((address_space(3))) void*)l, 16, 0, 0);
}

// ---------------- 128^2 BT GEMM (proven; G1/G3/G4) -----------------
// C[M,N] = A[M,K] * B[N,K]^T. LDS source-XOR swizzle, XCD-bijective tile remap.
template <typename OutT, bool MASK, bool ACC, int ZDIV, bool TMFAST>
__global__ __launch_bounds__(256) void gemm_bt(
    const u16* __restrict__ A, long sA1, long sA0, int lda,
    const u16* __restrict__ Bm, long sB1, long sB0, int ldb,
    OutT* __restrict__ C, long sC1, long sC0, int ldc,
    int K, const u32* __restrict__ maskbits) {
  constexpr int BK = 64;
  __shared__ u16 sA[128 * BK];
  __shared__ u16 sB[128 * BK];
  const int z = blockIdx.z;
  const int z1 = z / ZDIV, z0 = z % ZDIV;
  A += z1 * sA1 + z0 * sA0;
  Bm += z1 * sB1 + z0 * sB0;
  C += z1 * sC1 + z0 * sC0;
  const int gx = gridDim.x, gy = gridDim.y;
  const int nwg = gx * gy;
  const int lin = blockIdx.y * gx + blockIdx.x;
  const int q8 = nwg >> 3, r8 = nwg & 7;
  const int xcd = lin & 7, idx = lin >> 3;
  const int swz = (xcd < r8 ? xcd * (q8 + 1) : r8 * (q8 + 1) + (xcd - r8) * q8) + idx;
  const int tm = TMFAST ? (swz % gy) : (swz / gx);
  const int tn = TMFAST ? (swz / gy) : (swz % gx);
  const int t = threadIdx.x;
  const int lane = t & 63, wave = t >> 6;
  const int wm = (wave >> 1) * 64, wn = (wave & 1) * 64;
  const int srow = t >> 3;
  const int scol = (((t & 7) ^ (srow & 7))) * 8;
  const u16* Ag = A + (long)(tm * 128 + srow) * lda + scol;
  const u16* Bg = Bm + (long)(tn * 128 + srow) * ldb + scol;
  u16* lA = sA + t * 8;
  u16* lB = sB + t * 8;
  const int lr = lane & 15;
  const int hi = lane >> 4;
  const int x7 = lr & 7;
  f32x4 acc[4][4] = {};
  const int nk = K / BK;
  for (int kt = 0; kt < nk; ++kt) {
    const u16* Agk = Ag + kt * BK;
    const u16* Bgk = Bg + kt * BK;
#pragma unroll
    for (int j = 0; j < 4; ++j) gload16(Agk + (long)j * 32 * lda, lA + j * 2048);
#pragma unroll
    for (int j = 0; j < 4; ++j) gload16(Bgk + (long)j * 32 * ldb, lB + j * 2048);
    __syncthreads();
#pragma unroll
    for (int kk = 0; kk < 2; ++kk) {
      bf16x8 af[4], bfr[4];
#pragma unroll
      for (int mi = 0; mi < 4; ++mi)
        af[mi] = *(const bf16x8*)&sA[(wm + mi * 16 + lr) * BK + (((kk * 4 + hi) ^ x7) << 3)];
#pragma unroll
      for (int ni = 0; ni < 4; ++ni)
        bfr[ni] = *(const bf16x8*)&sB[(wn + ni * 16 + lr) * BK + (((kk * 4 + hi) ^ x7) << 3)];
#pragma unroll
      for (int mi = 0; mi < 4; ++mi)
#pragma unroll
        for (int ni = 0; ni < 4; ++ni)
          acc[mi][ni] = __builtin_amdgcn_mfma_f32_16x16x32_bf16(af[mi], bfr[ni], acc[mi][ni], 0, 0, 0);
    }
    __syncthreads();
  }
  const int r0 = tm * 128 + wm + (hi << 2);
  const int c0 = tn * 128 + wn + lr;
#pragma unroll
  for (int mi = 0; mi < 4; ++mi) {
#pragma unroll
    for (int j = 0; j < 4; ++j) {
      const int row = r0 + mi * 16 + j;
#pragma unroll
      for (int ni = 0; ni < 4; ++ni) {
        const int col = c0 + ni * 16;
        float v = acc[mi][ni][j];
        if (MASK) {
          const int g = col & (F_ - 1);
          const u32 w = maskbits[row * (F_ / 32) + (g >> 5)];
          if (!((w >> (g & 31)) & 1u)) v = 0.0f;
        }
        const long idx = (long)row * ldc + col;
        if constexpr (ACC) {
          C[idx] += v;
        } else if constexpr (sizeof(OutT) == 2) {
          C[idx] = (OutT)f2bf(v);
        } else {
          C[idx] = (OutT)v;
        }
      }
    }
  }
}

// ---------------- 256^2 deep-buffered BT GEMM (G2) -----------------
// 512 thr = 8 waves (2M x 4N); per-wave 128x64 output = 8mi x 4ni frags.
// Double-buffered 128 KiB LDS; per K-iter: issue next tile's global_load_lds
// FIRST, then ds_read+MFMA current, then one __syncthreads (late vmcnt drain).
template <bool MASK>
__global__ __launch_bounds__(512, 2) void gemm_bt256(
    const u16* __restrict__ A, long sAz, int lda,
    const u16* __restrict__ Bm, long sBz, int ldb,
    u16* __restrict__ C, long sCz, int ldc,
    int K, const u32* __restrict__ maskbits) {
  constexpr int BK = 64;
  __shared__ u16 lds[2 * 2 * 256 * BK];  // 128 KiB: [buf][A|B][256][64]
  const int z = blockIdx.z;
  A += (long)z * sAz;
  Bm += (long)z * sBz;
  C += (long)z * sCz;
  // XCD-bijective remap within z-slice
  const int gx = gridDim.x, gy = gridDim.y;
  const int nwg = gx * gy;
  const int lin = blockIdx.y * gx + blockIdx.x;
  const int q8 = nwg >> 3, r8 = nwg & 7;
  const int xcd = lin & 7, idx = lin >> 3;
  const int swz = (xcd < r8 ? xcd * (q8 + 1) : r8 * (q8 + 1) + (xcd - r8) * q8) + idx;
  const int tm = swz / gx, tn = swz % gx;
  const int t = threadIdx.x;
  const int lane = t & 63, wave = t >> 6;
  const int wmr = (wave >> 2) * 128;   // wave M-origin (2 rows of waves)
  const int wnr = (wave & 3) * 64;     // wave N-origin (4 cols of waves)
  const int srow = t >> 3;             // 0..63
  const int scol = (((t & 7) ^ (srow & 7))) * 8;
  const u16* Ag = A + (long)(tm * 256 + srow) * lda + scol;
  const u16* Bg = Bm + (long)(tn * 256 + srow) * ldb + scol;
  const int lr = lane & 15;
  const int hi = lane >> 4;
  const int x7 = lr & 7;
  f32x4 acc[8][4] = {};
  const int nk = K / BK;
  // prologue: stage tile 0 into buf 0
  {
    u16* lA = lds + t * 8;
    u16* lB = lds + 16384 + t * 8;
#pragma unroll
    for (int j = 0; j < 4; ++j) gload16(Ag + (long)j * 64 * lda, lA + j * 4096);
#pragma unroll
    for (int j = 0; j < 4; ++j) gload16(Bg + (long)j * 64 * ldb, lB + j * 4096);
  }
  __syncthreads();  // drains vmcnt(0)
  for (int kt = 0; kt < nk; ++kt) {
    const int c = kt & 1;
    const u16* sAc = lds + c * 32768;
    const u16* sBc = lds + c * 32768 + 16384;
    if (kt + 1 < nk) {  // issue next tile's loads FIRST (land during compute)
      u16* lA = lds + (c ^ 1) * 32768 + t * 8;
      u16* lB = lds + (c ^ 1) * 32768 + 16384 + t * 8;
      const u16* Agk = Ag + (kt + 1) * BK;
      const u16* Bgk = Bg + (kt + 1) * BK;
#pragma unroll
      for (int j = 0; j < 4; ++j) gload16(Agk + (long)j * 64 * lda, lA + j * 4096);
#pragma unroll
      for (int j = 0; j < 4; ++j) gload16(Bgk + (long)j * 64 * ldb, lB + j * 4096);
    }
    bf16x8 bfr[4][2], af[4][2];
#pragma unroll
    for (int ni = 0; ni < 4; ++ni)
#pragma unroll
      for (int kk = 0; kk < 2; ++kk)
        bfr[ni][kk] = *(const bf16x8*)&sBc[(wnr + ni * 16 + lr) * BK + (((kk * 4 + hi) ^ x7) << 3)];
#pragma unroll
    for (int mi = 0; mi < 4; ++mi)
#pragma unroll
      for (int kk = 0; kk < 2; ++kk)
        af[mi][kk] = *(const bf16x8*)&sAc[(wmr + mi * 16 + lr) * BK + (((kk * 4 + hi) ^ x7) << 3)];
#pragma unroll
    for (int kk = 0; kk < 2; ++kk)
#pragma unroll
      for (int mi = 0; mi < 4; ++mi)
#pragma unroll
        for (int ni = 0; ni < 4; ++ni)
          acc[mi][ni] = __builtin_amdgcn_mfma_f32_16x16x32_bf16(af[mi][kk], bfr[ni][kk], acc[mi][ni], 0, 0, 0);
#pragma unroll
    for (int mi = 0; mi < 4; ++mi)
#pragma unroll
      for (int kk = 0; kk < 2; ++kk)
        af[mi][kk] = *(const bf16x8*)&sAc[(wmr + 64 + mi * 16 + lr) * BK + (((kk * 4 + hi) ^ x7) << 3)];
#pragma unroll
    for (int kk = 0; kk < 2; ++kk)
#pragma unroll
      for (int mi = 0; mi < 4; ++mi)
#pragma unroll
        for (int ni = 0; ni < 4; ++ni)
          acc[mi + 4][ni] = __builtin_amdgcn_mfma_f32_16x16x32_bf16(af[mi][kk], bfr[ni][kk], acc[mi + 4][ni], 0, 0, 0);
    __syncthreads();  // drains vmcnt(0): next tile ready; prev buf free
  }
  // epilogue: row=(lane>>4)*4+reg, col=lane&15 ; nt stores (vw is a write-once stream)
  const int r0 = tm * 256 + wmr + (hi << 2);
  const int c0 = tn * 256 + wnr + lr;
#pragma unroll
  for (int mi = 0; mi < 8; ++mi) {
#pragma unroll
    for (int j = 0; j < 4; ++j) {
      const int row = r0 + mi * 16 + j;
#pragma unroll
      for (int ni = 0; ni < 4; ++ni) {
        const int col = c0 + ni * 16;
        float v = acc[mi][ni][j];
        if (MASK) {
          const int g = col & (F_ - 1);
          const u32 w = maskbits[row * (F_ / 32) + (g >> 5)];
          if (!((w >> (g & 31)) & 1u)) v = 0.0f;
        }
        __builtin_nontemporal_store((u16)f2bf(v), &C[(long)row * ldc + col]);
      }
    }
  }
}

// ---------------- prep kernels -----------------

__global__ void k_detect_mask(const u32* __restrict__ m, int* flag) {
  const int gid = blockIdx.x * 256 + threadIdx.x;  // 64 KB = 16384 words
  const u32 w = m[gid];
  const u64 b = __ballot((w & 0xFFFFFF00u) != 0u);
  if ((threadIdx.x & 63) == 0 && b) atomicOr(flag, 1);
}

__global__ void k_pack_mask(const void* __restrict__ m, u64* __restrict__ bits,
                            const int* __restrict__ flag) {
  const long i = (long)blockIdx.x * 256 + threadIdx.x;
  const int u8mode = *flag;
  const int v = u8mode ? (int)((const unsigned char*)m)[i] : ((const int*)m)[i];
  const u64 b = __ballot(v != 0);
  if ((threadIdx.x & 63) == 0) bits[i >> 6] = b;
}

__global__ void k_cast_bf4(const float* __restrict__ in, u16* __restrict__ out, long n4) {
  const long i = (long)blockIdx.x * 256 + threadIdx.x;
  if (i < n4) {
    const float4 v = ((const float4*)in)[i];
    ushort4 o;
    o.x = f2bf(v.x); o.y = f2bf(v.y); o.z = f2bf(v.z); o.w = f2bf(v.w);
    ((ushort4*)out)[i] = o;
  }
}

__global__ void k_ln_transpose(const float* __restrict__ uf, const float* __restrict__ sc,
                               u16* __restrict__ out) {
  __shared__ float tile[32][33];
  const int b = blockIdx.z;
  const int g0 = blockIdx.x * 32, k0 = blockIdx.y * 32;
  const int x = threadIdx.x, y = threadIdx.y;
#pragma unroll
  for (int i = 0; i < 4; ++i) {
    const int k = k0 + y + i * 8;
    tile[y + i * 8][x] = uf[((long)(b * S_ + k)) * F_ + g0 + x] / sc[b * S_ + k];
  }
  __syncthreads();
#pragma unroll
  for (int i = 0; i < 4; ++i) {
    const int g = g0 + y + i * 8;
    out[((long)(b * F_ + g)) * S_ + k0 + x] = f2bf(tile[x][y + i * 8]);
  }
}

__global__ void k_transpose_cast(const float* __restrict__ in, u16* __restrict__ out, int R, int Cc) {
  __shared__ float tile[32][33];
  const int c0 = blockIdx.x * 32, r0 = blockIdx.y * 32;
  const int x = threadIdx.x, y = threadIdx.y;
#pragma unroll
  for (int i = 0; i < 4; ++i)
    tile[y + i * 8][x] = in[(long)(r0 + y + i * 8) * Cc + c0 + x];
  __syncthreads();
#pragma unroll
  for (int i = 0; i < 4; ++i)
    out[(long)(c0 + y + i * 8) * R + r0 + x] = f2bf(tile[x][y + i * 8]);
}

__global__ void k_reduce_out(const float* __restrict__ part, float* __restrict__ out,
                             long n, int ns) {
  const long i = (long)blockIdx.x * 256 + threadIdx.x;
  const long n4 = n / 4;
  if (i < n4) {
    float4 a = ((const float4*)part)[i];
    for (int s = 1; s < ns; ++s) {
      const float4 b = ((const float4*)part)[i + s * n4];
      a.x += b.x; a.y += b.y; a.z += b.z; a.w += b.w;
    }
    ((float4*)out)[i] = a;
  }
}

// ---------------- launch -----------------
extern "C" void kernel_launch(void* const* d_in, const int* in_sizes, int n_in,
                              void* d_out, int out_size, void* d_ws, size_t ws_size,
                              hipStream_t stream) {
  const float* up_facts = (const float*)d_in[0];
  const float* hook_scale = (const float*)d_in[1];
  const float* probs = (const float*)d_in[2];
  const float* down_enc = (const float*)d_in[3];
  const float* up_dec = (const float*)d_in[4];
  const float* w_ov = (const float*)d_in[5];
  const void* cmask = d_in[6];
  float* out = (float*)d_out;

  char* base = (char*)d_ws;
  size_t off = 0;
  auto al = [](size_t b) { return (b + 255) & ~(size_t)255; };
  auto take = [&](size_t bytes) -> char* { char* r = base + off; off += al(bytes); return r; };

  u16* probs_bf = (u16*)take((size_t)B_ * H_ * S_ * S_ * 2);
  u16* upT_post = (u16*)take((size_t)B_ * F_ * S_ * 2);
  u16* dE_bf    = (u16*)take((size_t)F_ * D_ * 2);
  u16* wov_bf   = (u16*)take((size_t)H_ * D_ * D_ * 2);
  u16* upT_dec  = (u16*)take((size_t)F_ * D_ * 2);
  u64* mbits    = (u64*)take((size_t)F_ * F_ / 8);
  int* flag     = (int*)take(256);
  const size_t fixed_end = off;

  int NH = 1;
  for (int cand = 4; cand >= 2; --cand) {
    if (H_ % cand) continue;
    const size_t need = fixed_end + al((size_t)cand * F_ * D_ * 2)
                      + al((size_t)cand * F_ * F_ * 2)
                      + al((size_t)B_ * S_ * cand * F_ * 2)
                      + al((size_t)4 * S_ * F_ * 4);
    if (ws_size >= need) { NH = cand; break; }
  }
  u16* tmp_c  = (u16*)take((size_t)NH * F_ * D_ * 2);       // [nh][f][i]
  u16* vw_c   = (u16*)take((size_t)NH * F_ * F_ * 2);       // [f][nh*F+g]
  u16* pup_c  = (u16*)take((size_t)B_ * S_ * NH * F_ * 2);  // [b][q][nh][g]
  float* part = (float*)take((size_t)4 * S_ * F_ * 4);      // [s*2+b][q][f]

  hipMemsetAsync(flag, 0, 4, stream);
  k_detect_mask<<<64, 256, 0, stream>>>((const u32*)cmask, flag);
  k_pack_mask<<<(F_ * (long)F_) / 256, 256, 0, stream>>>(cmask, mbits, flag);
  k_cast_bf4<<<((long)B_ * H_ * S_ * S_ / 4 + 255) / 256, 256, 0, stream>>>(
      probs, probs_bf, (long)B_ * H_ * S_ * S_ / 4);
  k_cast_bf4<<<((long)F_ * D_ / 4 + 255) / 256, 256, 0, stream>>>(down_enc, dE_bf, (long)F_ * D_ / 4);
  k_cast_bf4<<<((long)H_ * D_ * D_ / 4 + 255) / 256, 256, 0, stream>>>(w_ov, wov_bf, (long)H_ * D_ * D_ / 4);
  k_ln_transpose<<<dim3(F_ / 32, S_ / 32, B_), dim3(32, 8), 0, stream>>>(up_facts, hook_scale, upT_post);
  k_transpose_cast<<<dim3(F_ / 32, D_ / 32, 1), dim3(32, 8), 0, stream>>>(up_dec, upT_dec, D_, F_);

  const int ldK = NH * F_;
  for (int h0 = 0; h0 < H_; h0 += NH) {
    // G1: tmp_c[nh][f,i] = dE[f,:] . W_OV[h0+nh,i,:]
    gemm_bt<u16, false, false, 1, false><<<dim3(D_ / 128, F_ / 128, NH), 256, 0, stream>>>(
        dE_bf, 0, 0, D_,
        wov_bf + (size_t)h0 * D_ * D_, (long)D_ * D_, 0, D_,
        tmp_c, (long)F_ * D_, 0, D_, D_, nullptr);
    // G2 (256^2 deep): vw_c[f][nh*F+g] = tmp_c[nh][f,:] . upT_dec[g,:], masked
    gemm_bt256<true><<<dim3(F_ / 256, F_ / 256, NH), 512, 0, stream>>>(
        tmp_c, (long)F_ * D_, D_,
        upT_dec, 0, D_,
        vw_c, (long)F_, ldK, D_, (const u32*)mbits);
    // G3: pup_c[b][q][nh][g] = probs[b,h0+nh][q,:] . upT_post[b][g,:]
    gemm_bt<u16, false, false, 2, false><<<dim3(F_ / 128, S_ / 128, NH * B_), 256, 0, stream>>>(
        probs_bf + (size_t)h0 * S_ * S_, (long)S_ * S_, (long)H_ * S_ * S_, S_,
        upT_post, 0, (long)F_ * S_, S_,
        pup_c, (long)F_, (long)S_ * ldK, ldK, S_, nullptr);
    // G4: part[s*2+b][q,f] (+)= pup_c[b][q,:] . vw_c[f,:]  over K=NH*F, split-K 2
    if (h0 == 0)
      gemm_bt<float, false, false, 2, true><<<dim3(F_ / 128, S_ / 128, 4), 256, 0, stream>>>(
          pup_c, (long)(ldK / 2), (long)S_ * ldK, ldK,
          vw_c, (long)(ldK / 2), 0, ldK,
          part, (long)2 * S_ * F_, (long)S_ * F_, F_, ldK / 2, nullptr);
    else
      gemm_bt<float, false, true, 2, true><<<dim3(F_ / 128, S_ / 128, 4), 256, 0, stream>>>(
          pup_c, (long)(ldK / 2), (long)S_ * ldK, ldK,
          vw_c, (long)(ldK / 2), 0, ldK,
          part, (long)2 * S_ * F_, (long)S_ * F_, F_, ldK / 2, nullptr);
  }
  const long n_out = (long)B_ * S_ * F_;
  k_reduce_out<<<(n_out / 4 + 255) / 256, 256, 0, stream>>>(part, out, n_out, 4);
}

// Round 5
// 1210.556 us; speedup vs baseline: 1.0804x; 1.0804x over previous
//
#include <hip/hip_runtime.h>

#define B_ 2
#define S_ 512
#define F_ 4096
#define D_ 768
#define H_ 12

typedef __attribute__((ext_vector_type(8))) short bf16x8;
typedef __attribute__((ext_vector_type(4))) float f32x4;
typedef unsigned short u16;
typedef unsigned int u32;
typedef unsigned long long u64;

__device__ inline u16 f2bf(float f) {
  u32 u = __float_as_uint(f);
  u32 r = (u + 0x7fffu + ((u >> 16) & 1u)) >> 16;  // RNE
  return (u16)r;
}

__device__ inline void gload16(const void* g, void* l) {
  __builtin_amdgcn_global_load_lds((const __attribute__((address_space(1))) void*)g,
                                   (__attribute__((address_space(3))) void*)l, 16, 0, 0);
}

// ---------------- 128^2 BT GEMM (proven; G1/G3) -----------------
template <typename OutT, bool MASK, bool ACC, int ZDIV, bool TMFAST>
__global__ __launch_bounds__(256) void gemm_bt(
    const u16* __restrict__ A, long sA1, long sA0, int lda,
    const u16* __restrict__ Bm, long sB1, long sB0, int ldb,
    OutT* __restrict__ C, long sC1, long sC0, int ldc,
    int K, const u32* __restrict__ maskbits) {
  constexpr int BK = 64;
  __shared__ u16 sA[128 * BK];
  __shared__ u16 sB[128 * BK];
  const int z = blockIdx.z;
  const int z1 = z / ZDIV, z0 = z % ZDIV;
  A += z1 * sA1 + z0 * sA0;
  Bm += z1 * sB1 + z0 * sB0;
  C += z1 * sC1 + z0 * sC0;
  const int gx = gridDim.x, gy = gridDim.y;
  const int nwg = gx * gy;
  const int lin = blockIdx.y * gx + blockIdx.x;
  const int q8 = nwg >> 3, r8 = nwg & 7;
  const int xcd = lin & 7, idx = lin >> 3;
  const int swz = (xcd < r8 ? xcd * (q8 + 1) : r8 * (q8 + 1) + (xcd - r8) * q8) + idx;
  const int tm = TMFAST ? (swz % gy) : (swz / gx);
  const int tn = TMFAST ? (swz / gy) : (swz % gx);
  const int t = threadIdx.x;
  const int lane = t & 63, wave = t >> 6;
  const int wm = (wave >> 1) * 64, wn = (wave & 1) * 64;
  const int srow = t >> 3;
  const int scol = (((t & 7) ^ (srow & 7))) * 8;
  const u16* Ag = A + (long)(tm * 128 + srow) * lda + scol;
  const u16* Bg = Bm + (long)(tn * 128 + srow) * ldb + scol;
  u16* lA = sA + t * 8;
  u16* lB = sB + t * 8;
  const int lr = lane & 15;
  const int hi = lane >> 4;
  const int x7 = lr & 7;
  f32x4 acc[4][4] = {};
  const int nk = K / BK;
  for (int kt = 0; kt < nk; ++kt) {
    const u16* Agk = Ag + kt * BK;
    const u16* Bgk = Bg + kt * BK;
#pragma unroll
    for (int j = 0; j < 4; ++j) gload16(Agk + (long)j * 32 * lda, lA + j * 2048);
#pragma unroll
    for (int j = 0; j < 4; ++j) gload16(Bgk + (long)j * 32 * ldb, lB + j * 2048);
    __syncthreads();
#pragma unroll
    for (int kk = 0; kk < 2; ++kk) {
      bf16x8 af[4], bfr[4];
#pragma unroll
      for (int mi = 0; mi < 4; ++mi)
        af[mi] = *(const bf16x8*)&sA[(wm + mi * 16 + lr) * BK + (((kk * 4 + hi) ^ x7) << 3)];
#pragma unroll
      for (int ni = 0; ni < 4; ++ni)
        bfr[ni] = *(const bf16x8*)&sB[(wn + ni * 16 + lr) * BK + (((kk * 4 + hi) ^ x7) << 3)];
#pragma unroll
      for (int mi = 0; mi < 4; ++mi)
#pragma unroll
        for (int ni = 0; ni < 4; ++ni)
          acc[mi][ni] = __builtin_amdgcn_mfma_f32_16x16x32_bf16(af[mi], bfr[ni], acc[mi][ni], 0, 0, 0);
    }
    __syncthreads();
  }
  const int r0 = tm * 128 + wm + (hi << 2);
  const int c0 = tn * 128 + wn + lr;
#pragma unroll
  for (int mi = 0; mi < 4; ++mi) {
#pragma unroll
    for (int j = 0; j < 4; ++j) {
      const int row = r0 + mi * 16 + j;
#pragma unroll
      for (int ni = 0; ni < 4; ++ni) {
        const int col = c0 + ni * 16;
        float v = acc[mi][ni][j];
        if (MASK) {
          const int g = col & (F_ - 1);
          const u32 w = maskbits[row * (F_ / 32) + (g >> 5)];
          if (!((w >> (g & 31)) & 1u)) v = 0.0f;
        }
        const long idx = (long)row * ldc + col;
        if constexpr (ACC) {
          C[idx] += v;
        } else if constexpr (sizeof(OutT) == 2) {
          C[idx] = (OutT)f2bf(v);
        } else {
          C[idx] = (OutT)v;
        }
      }
    }
  }
}

// ---------------- 64x128 BT GEMM (G4: skinny-M, 4 blocks/CU) -----------------
// BM=64, BN=128, 4 waves (2M x 2N), wave-tile 32x64 = 2mi x 4ni frags.
// Same 2-phase structure / XOR swizzle / m89 C-layout as gemm_bt. f32 out, opt ACC.
// z = z1*2+z0 (z1 = split-K slice, z0 = batch); M-fast XCD swizzle.
template <bool ACC>
__global__ __launch_bounds__(256) void gemm_bt64(
    const u16* __restrict__ A, long sA1, long sA0, int lda,
    const u16* __restrict__ Bm, long sB1, long sB0, int ldb,
    float* __restrict__ C, long sC1, long sC0, int ldc,
    int K) {
  constexpr int BK = 64;
  __shared__ u16 sA[64 * BK];    //  8 KB
  __shared__ u16 sB[128 * BK];   // 16 KB
  const int z = blockIdx.z;
  const int z1 = z >> 1, z0 = z & 1;
  A += z1 * sA1 + z0 * sA0;
  Bm += z1 * sB1 + z0 * sB0;
  C += z1 * sC1 + z0 * sC0;
  const int gx = gridDim.x, gy = gridDim.y;
  const int nwg = gx * gy;
  const int lin = blockIdx.y * gx + blockIdx.x;
  const int q8 = nwg >> 3, r8 = nwg & 7;
  const int xcd = lin & 7, idx = lin >> 3;
  const int swz = (xcd < r8 ? xcd * (q8 + 1) : r8 * (q8 + 1) + (xcd - r8) * q8) + idx;
  const int tm = swz % gy;  // M fast: all M-tiles of one B-panel adjacent on an XCD
  const int tn = swz / gy;
  const int t = threadIdx.x;
  const int lane = t & 63, wave = t >> 6;
  const int wm = (wave >> 1) * 32, wn = (wave & 1) * 64;
  const int srow = t >> 3;
  const int scol = (((t & 7) ^ (srow & 7))) * 8;
  const u16* Ag = A + (long)(tm * 64 + srow) * lda + scol;
  const u16* Bg = Bm + (long)(tn * 128 + srow) * ldb + scol;
  u16* lA = sA + t * 8;
  u16* lB = sB + t * 8;
  const int lr = lane & 15;
  const int hi = lane >> 4;
  const int x7 = lr & 7;
  f32x4 acc[2][4] = {};
  const int nk = K / BK;
  for (int kt = 0; kt < nk; ++kt) {
    const u16* Agk = Ag + kt * BK;
    const u16* Bgk = Bg + kt * BK;
#pragma unroll
    for (int j = 0; j < 2; ++j) gload16(Agk + (long)j * 32 * lda, lA + j * 2048);
#pragma unroll
    for (int j = 0; j < 4; ++j) gload16(Bgk + (long)j * 32 * ldb, lB + j * 2048);
    __syncthreads();
#pragma unroll
    for (int kk = 0; kk < 2; ++kk) {
      bf16x8 af[2], bfr[4];
#pragma unroll
      for (int mi = 0; mi < 2; ++mi)
        af[mi] = *(const bf16x8*)&sA[(wm + mi * 16 + lr) * BK + (((kk * 4 + hi) ^ x7) << 3)];
#pragma unroll
      for (int ni = 0; ni < 4; ++ni)
        bfr[ni] = *(const bf16x8*)&sB[(wn + ni * 16 + lr) * BK + (((kk * 4 + hi) ^ x7) << 3)];
#pragma unroll
      for (int mi = 0; mi < 2; ++mi)
#pragma unroll
        for (int ni = 0; ni < 4; ++ni)
          acc[mi][ni] = __builtin_amdgcn_mfma_f32_16x16x32_bf16(af[mi], bfr[ni], acc[mi][ni], 0, 0, 0);
    }
    __syncthreads();
  }
  const int r0 = tm * 64 + wm + (hi << 2);
  const int c0 = tn * 128 + wn + lr;
#pragma unroll
  for (int mi = 0; mi < 2; ++mi) {
#pragma unroll
    for (int j = 0; j < 4; ++j) {
      const int row = r0 + mi * 16 + j;
#pragma unroll
      for (int ni = 0; ni < 4; ++ni) {
        const int col = c0 + ni * 16;
        const long idx = (long)row * ldc + col;
        if constexpr (ACC) C[idx] += acc[mi][ni][j];
        else               C[idx] = acc[mi][ni][j];
      }
    }
  }
}

// ---------------- 256^2 deep-buffered BT GEMM (G2) -----------------
template <bool MASK>
__global__ __launch_bounds__(512, 2) void gemm_bt256(
    const u16* __restrict__ A, long sAz, int lda,
    const u16* __restrict__ Bm, long sBz, int ldb,
    u16* __restrict__ C, long sCz, int ldc,
    int K, const u32* __restrict__ maskbits) {
  constexpr int BK = 64;
  __shared__ u16 lds[2 * 2 * 256 * BK];  // 128 KiB: [buf][A|B][256][64]
  const int z = blockIdx.z;
  A += (long)z * sAz;
  Bm += (long)z * sBz;
  C += (long)z * sCz;
  const int gx = gridDim.x, gy = gridDim.y;
  const int nwg = gx * gy;
  const int lin = blockIdx.y * gx + blockIdx.x;
  const int q8 = nwg >> 3, r8 = nwg & 7;
  const int xcd = lin & 7, idx = lin >> 3;
  const int swz = (xcd < r8 ? xcd * (q8 + 1) : r8 * (q8 + 1) + (xcd - r8) * q8) + idx;
  const int tm = swz / gx, tn = swz % gx;
  const int t = threadIdx.x;
  const int lane = t & 63, wave = t >> 6;
  const int wmr = (wave >> 2) * 128;
  const int wnr = (wave & 3) * 64;
  const int srow = t >> 3;
  const int scol = (((t & 7) ^ (srow & 7))) * 8;
  const u16* Ag = A + (long)(tm * 256 + srow) * lda + scol;
  const u16* Bg = Bm + (long)(tn * 256 + srow) * ldb + scol;
  const int lr = lane & 15;
  const int hi = lane >> 4;
  const int x7 = lr & 7;
  f32x4 acc[8][4] = {};
  const int nk = K / BK;
  {
    u16* lA = lds + t * 8;
    u16* lB = lds + 16384 + t * 8;
#pragma unroll
    for (int j = 0; j < 4; ++j) gload16(Ag + (long)j * 64 * lda, lA + j * 4096);
#pragma unroll
    for (int j = 0; j < 4; ++j) gload16(Bg + (long)j * 64 * ldb, lB + j * 4096);
  }
  __syncthreads();
  for (int kt = 0; kt < nk; ++kt) {
    const int c = kt & 1;
    const u16* sAc = lds + c * 32768;
    const u16* sBc = lds + c * 32768 + 16384;
    if (kt + 1 < nk) {
      u16* lA = lds + (c ^ 1) * 32768 + t * 8;
      u16* lB = lds + (c ^ 1) * 32768 + 16384 + t * 8;
      const u16* Agk = Ag + (kt + 1) * BK;
      const u16* Bgk = Bg + (kt + 1) * BK;
#pragma unroll
      for (int j = 0; j < 4; ++j) gload16(Agk + (long)j * 64 * lda, lA + j * 4096);
#pragma unroll
      for (int j = 0; j < 4; ++j) gload16(Bgk + (long)j * 64 * ldb, lB + j * 4096);
    }
    bf16x8 bfr[4][2], af[4][2];
#pragma unroll
    for (int ni = 0; ni < 4; ++ni)
#pragma unroll
      for (int kk = 0; kk < 2; ++kk)
        bfr[ni][kk] = *(const bf16x8*)&sBc[(wnr + ni * 16 + lr) * BK + (((kk * 4 + hi) ^ x7) << 3)];
#pragma unroll
    for (int mi = 0; mi < 4; ++mi)
#pragma unroll
      for (int kk = 0; kk < 2; ++kk)
        af[mi][kk] = *(const bf16x8*)&sAc[(wmr + mi * 16 + lr) * BK + (((kk * 4 + hi) ^ x7) << 3)];
#pragma unroll
    for (int kk = 0; kk < 2; ++kk)
#pragma unroll
      for (int mi = 0; mi < 4; ++mi)
#pragma unroll
        for (int ni = 0; ni < 4; ++ni)
          acc[mi][ni] = __builtin_amdgcn_mfma_f32_16x16x32_bf16(af[mi][kk], bfr[ni][kk], acc[mi][ni], 0, 0, 0);
#pragma unroll
    for (int mi = 0; mi < 4; ++mi)
#pragma unroll
      for (int kk = 0; kk < 2; ++kk)
        af[mi][kk] = *(const bf16x8*)&sAc[(wmr + 64 + mi * 16 + lr) * BK + (((kk * 4 + hi) ^ x7) << 3)];
#pragma unroll
    for (int kk = 0; kk < 2; ++kk)
#pragma unroll
      for (int mi = 0; mi < 4; ++mi)
#pragma unroll
        for (int ni = 0; ni < 4; ++ni)
          acc[mi + 4][ni] = __builtin_amdgcn_mfma_f32_16x16x32_bf16(af[mi][kk], bfr[ni][kk], acc[mi + 4][ni], 0, 0, 0);
    __syncthreads();
  }
  // epilogue: normal stores (vw must stay L2/L3-resident for G4 — NT regressed G4 by 14%)
  const int r0 = tm * 256 + wmr + (hi << 2);
  const int c0 = tn * 256 + wnr + lr;
#pragma unroll
  for (int mi = 0; mi < 8; ++mi) {
#pragma unroll
    for (int j = 0; j < 4; ++j) {
      const int row = r0 + mi * 16 + j;
#pragma unroll
      for (int ni = 0; ni < 4; ++ni) {
        const int col = c0 + ni * 16;
        float v = acc[mi][ni][j];
        if (MASK) {
          const int g = col & (F_ - 1);
          const u32 w = maskbits[row * (F_ / 32) + (g >> 5)];
          if (!((w >> (g & 31)) & 1u)) v = 0.0f;
        }
        C[(long)row * ldc + col] = (u16)f2bf(v);
      }
    }
  }
}

// ---------------- prep kernels -----------------

__global__ void k_detect_mask(const u32* __restrict__ m, int* flag) {
  const int gid = blockIdx.x * 256 + threadIdx.x;  // 64 KB = 16384 words
  const u32 w = m[gid];
  const u64 b = __ballot((w & 0xFFFFFF00u) != 0u);
  if ((threadIdx.x & 63) == 0 && b) atomicOr(flag, 1);
}

__global__ void k_pack_mask(const void* __restrict__ m, u64* __restrict__ bits,
                            const int* __restrict__ flag) {
  const long i = (long)blockIdx.x * 256 + threadIdx.x;
  const int u8mode = *flag;
  const int v = u8mode ? (int)((const unsigned char*)m)[i] : ((const int*)m)[i];
  const u64 b = __ballot(v != 0);
  if ((threadIdx.x & 63) == 0) bits[i >> 6] = b;
}

__global__ void k_cast_bf4(const float* __restrict__ in, u16* __restrict__ out, long n4) {
  const long i = (long)blockIdx.x * 256 + threadIdx.x;
  if (i < n4) {
    const float4 v = ((const float4*)in)[i];
    ushort4 o;
    o.x = f2bf(v.x); o.y = f2bf(v.y); o.z = f2bf(v.z); o.w = f2bf(v.w);
    ((ushort4*)out)[i] = o;
  }
}

__global__ void k_ln_transpose(const float* __restrict__ uf, const float* __restrict__ sc,
                               u16* __restrict__ out) {
  __shared__ float tile[32][33];
  const int b = blockIdx.z;
  const int g0 = blockIdx.x * 32, k0 = blockIdx.y * 32;
  const int x = threadIdx.x, y = threadIdx.y;
#pragma unroll
  for (int i = 0; i < 4; ++i) {
    const int k = k0 + y + i * 8;
    tile[y + i * 8][x] = uf[((long)(b * S_ + k)) * F_ + g0 + x] / sc[b * S_ + k];
  }
  __syncthreads();
#pragma unroll
  for (int i = 0; i < 4; ++i) {
    const int g = g0 + y + i * 8;
    out[((long)(b * F_ + g)) * S_ + k0 + x] = f2bf(tile[x][y + i * 8]);
  }
}

__global__ void k_transpose_cast(const float* __restrict__ in, u16* __restrict__ out, int R, int Cc) {
  __shared__ float tile[32][33];
  const int c0 = blockIdx.x * 32, r0 = blockIdx.y * 32;
  const int x = threadIdx.x, y = threadIdx.y;
#pragma unroll
  for (int i = 0; i < 4; ++i)
    tile[y + i * 8][x] = in[(long)(r0 + y + i * 8) * Cc + c0 + x];
  __syncthreads();
#pragma unroll
  for (int i = 0; i < 4; ++i)
    out[(long)(c0 + y + i * 8) * R + r0 + x] = f2bf(tile[x][y + i * 8]);
}

__global__ void k_reduce_out(const float* __restrict__ part, float* __restrict__ out,
                             long n, int ns) {
  const long i = (long)blockIdx.x * 256 + threadIdx.x;
  const long n4 = n / 4;
  if (i < n4) {
    float4 a = ((const float4*)part)[i];
    for (int s = 1; s < ns; ++s) {
      const float4 b = ((const float4*)part)[i + s * n4];
      a.x += b.x; a.y += b.y; a.z += b.z; a.w += b.w;
    }
    ((float4*)out)[i] = a;
  }
}

// ---------------- launch -----------------
extern "C" void kernel_launch(void* const* d_in, const int* in_sizes, int n_in,
                              void* d_out, int out_size, void* d_ws, size_t ws_size,
                              hipStream_t stream) {
  const float* up_facts = (const float*)d_in[0];
  const float* hook_scale = (const float*)d_in[1];
  const float* probs = (const float*)d_in[2];
  const float* down_enc = (const float*)d_in[3];
  const float* up_dec = (const float*)d_in[4];
  const float* w_ov = (const float*)d_in[5];
  const void* cmask = d_in[6];
  float* out = (float*)d_out;

  char* base = (char*)d_ws;
  size_t off = 0;
  auto al = [](size_t b) { return (b + 255) & ~(size_t)255; };
  auto take = [&](size_t bytes) -> char* { char* r = base + off; off += al(bytes); return r; };

  u16* probs_bf = (u16*)take((size_t)B_ * H_ * S_ * S_ * 2);
  u16* upT_post = (u16*)take((size_t)B_ * F_ * S_ * 2);
  u16* dE_bf    = (u16*)take((size_t)F_ * D_ * 2);
  u16* wov_bf   = (u16*)take((size_t)H_ * D_ * D_ * 2);
  u16* upT_dec  = (u16*)take((size_t)F_ * D_ * 2);
  u64* mbits    = (u64*)take((size_t)F_ * F_ / 8);
  int* flag     = (int*)take(256);
  const size_t fixed_end = off;

  int NH = 1;
  for (int cand = 4; cand >= 2; --cand) {
    if (H_ % cand) continue;
    const size_t need = fixed_end + al((size_t)cand * F_ * D_ * 2)
                      + al((size_t)cand * F_ * F_ * 2)
                      + al((size_t)B_ * S_ * cand * F_ * 2)
                      + al((size_t)4 * S_ * F_ * 4);
    if (ws_size >= need) { NH = cand; break; }
  }
  u16* tmp_c  = (u16*)take((size_t)NH * F_ * D_ * 2);       // [nh][f][i]
  u16* vw_c   = (u16*)take((size_t)NH * F_ * F_ * 2);       // [f][nh*F+g]
  u16* pup_c  = (u16*)take((size_t)B_ * S_ * NH * F_ * 2);  // [b][q][nh][g]
  float* part = (float*)take((size_t)4 * S_ * F_ * 4);      // [s*2+b][q][f]

  hipMemsetAsync(flag, 0, 4, stream);
  k_detect_mask<<<64, 256, 0, stream>>>((const u32*)cmask, flag);
  k_pack_mask<<<(F_ * (long)F_) / 256, 256, 0, stream>>>(cmask, mbits, flag);
  k_cast_bf4<<<((long)B_ * H_ * S_ * S_ / 4 + 255) / 256, 256, 0, stream>>>(
      probs, probs_bf, (long)B_ * H_ * S_ * S_ / 4);
  k_cast_bf4<<<((long)F_ * D_ / 4 + 255) / 256, 256, 0, stream>>>(down_enc, dE_bf, (long)F_ * D_ / 4);
  k_cast_bf4<<<((long)H_ * D_ * D_ / 4 + 255) / 256, 256, 0, stream>>>(w_ov, wov_bf, (long)H_ * D_ * D_ / 4);
  k_ln_transpose<<<dim3(F_ / 32, S_ / 32, B_), dim3(32, 8), 0, stream>>>(up_facts, hook_scale, upT_post);
  k_transpose_cast<<<dim3(F_ / 32, D_ / 32, 1), dim3(32, 8), 0, stream>>>(up_dec, upT_dec, D_, F_);

  const int ldK = NH * F_;
  for (int h0 = 0; h0 < H_; h0 += NH) {
    // G1: tmp_c[nh][f,i] = dE[f,:] . W_OV[h0+nh,i,:]
    gemm_bt<u16, false, false, 1, false><<<dim3(D_ / 128, F_ / 128, NH), 256, 0, stream>>>(
        dE_bf, 0, 0, D_,
        wov_bf + (size_t)h0 * D_ * D_, (long)D_ * D_, 0, D_,
        tmp_c, (long)F_ * D_, 0, D_, D_, nullptr);
    // G2 (256^2 deep): vw_c[f][nh*F+g] = tmp_c[nh][f,:] . upT_dec[g,:], masked
    gemm_bt256<true><<<dim3(F_ / 256, F_ / 256, NH), 512, 0, stream>>>(
        tmp_c, (long)F_ * D_, D_,
        upT_dec, 0, D_,
        vw_c, (long)F_, ldK, D_, (const u32*)mbits);
    // G3: pup_c[b][q][nh][g] = probs[b,h0+nh][q,:] . upT_post[b][g,:]
    gemm_bt<u16, false, false, 2, false><<<dim3(F_ / 128, S_ / 128, NH * B_), 256, 0, stream>>>(
        probs_bf + (size_t)h0 * S_ * S_, (long)S_ * S_, (long)H_ * S_ * S_, S_,
        upT_post, 0, (long)F_ * S_, S_,
        pup_c, (long)F_, (long)S_ * ldK, ldK, S_, nullptr);
    // G4 (64x128 tiles, 1024 blocks): part[s*2+b][q,f] (+)= pup_c . vw_c^T, split-K 2
    if (h0 == 0)
      gemm_bt64<false><<<dim3(F_ / 128, S_ / 64, 4), 256, 0, stream>>>(
          pup_c, (long)(ldK / 2), (long)S_ * ldK, ldK,
          vw_c, (long)(ldK / 2), 0, ldK,
          part, (long)2 * S_ * F_, (long)S_ * F_, F_, ldK / 2);
    else
      gemm_bt64<true><<<dim3(F_ / 128, S_ / 64, 4), 256, 0, stream>>>(
          pup_c, (long)(ldK / 2), (long)S_ * ldK, ldK,
          vw_c, (long)(ldK / 2), 0, ldK,
          part, (long)2 * S_ * F_, (long)S_ * F_, F_, ldK / 2);
  }
  const long n_out = (long)B_ * S_ * F_;
  k_reduce_out<<<(n_out / 4 + 255) / 256, 256, 0, stream>>>(part, out, n_out, 4);
}